// Round 1
// baseline (41.809 us; speedup 1.0000x reference)
//
#include <hip/hip_runtime.h>
#include <math.h>

#define HH 256
#define WW 256
#define NF 352
#define NV 192
#define SIGMA_F 0.7f
#define CUT_S (-16.0f)

__device__ __forceinline__ float fast_sigmoid(float x) {
    // 1/(1+exp(-x)); large |x| saturates correctly (exp->inf => 0, exp->0 => 1)
    return __builtin_amdgcn_rcpf(1.0f + __expf(-x));
}

// One block = one 16x16 pixel tile of one batch image.
__global__ __launch_bounds__(256) void sil_tile_kernel(
    const float* __restrict__ Rm, const float* __restrict__ obj_t,
    const float* __restrict__ obj_s, const float* __restrict__ verts,
    const int* __restrict__ faces, const float* __restrict__ Km,
    const float* __restrict__ keep_mask, const float* __restrict__ image_ref,
    float* __restrict__ out_image, float* __restrict__ loss_partials)
{
    __shared__ float co[NF * 9];
    __shared__ unsigned char fflag[NF];
    __shared__ unsigned short flist[NF];
    __shared__ int fcount;
    __shared__ float wsum[4];

    const int tid = threadIdx.x;
    const int b   = blockIdx.x >> 8;     // 256 tiles per batch image
    const int t   = blockIdx.x & 255;
    const int tx  = t & 15, ty = t >> 4;
    const int x0  = tx * 16, y0 = ty * 16;

    const float pxc = (float)x0 + 8.0f;  // tile center (half-extent 7.5 <= 8)
    const float pyc = (float)y0 + 8.0f;

    // ---- phase 1: per-face edge coefficients + conservative tile cull flag ----
    const float* Rb = Rm + b * 9;
    const float s  = obj_s[b];
    const float t0 = obj_t[b*3+0], t1 = obj_t[b*3+1], t2 = obj_t[b*3+2];
    const float K00 = Km[b*9+0], K02 = Km[b*9+2], K11 = Km[b*9+4], K12 = Km[b*9+5];

    for (int f = tid; f < NF; f += 256) {
        float X[3], Y[3];
        #pragma unroll
        for (int k = 0; k < 3; ++k) {
            int vi = faces[f*3 + k];
            const float* vp = verts + (b * NV + vi) * 3;
            float v0 = vp[0], v1 = vp[1], v2 = vp[2];
            float w0 = s * (v0*Rb[0] + v1*Rb[3] + v2*Rb[6] + t0);
            float w1 = s * (v0*Rb[1] + v1*Rb[4] + v2*Rb[7] + t1);
            float w2 = s * (v0*Rb[2] + v1*Rb[5] + v2*Rb[8] + t2);
            X[k] = (K00 * w0 / w2 + K02) * (float)WW;
            Y[k] = (K11 * w1 / w2 + K12) * (float)HH;
        }
        float e01x = X[1]-X[0], e01y = Y[1]-Y[0];
        float e02x = X[2]-X[0], e02y = Y[2]-Y[0];
        float area2 = e01x*e02y - e01y*e02x;
        float orient = (area2 >= 0.0f) ? 1.0f : -1.0f;
        float smin = 1e30f;
        #pragma unroll
        for (int k = 0; k < 3; ++k) {
            int k1 = (k == 2) ? 0 : k + 1;
            float ax = X[k], ay = Y[k];
            float ex = X[k1]-ax, ey = Y[k1]-ay;
            float inv = orient / (sqrtf(ex*ex + ey*ey) + 1e-8f) / SIGMA_F;
            float A = ex * inv;
            float B = -ey * inv;
            float C = inv * (ey*ax - ex*ay);
            co[f*9 + k*3 + 0] = A;
            co[f*9 + k*3 + 1] = B;
            co[f*9 + k*3 + 2] = C;
            // exact max of affine s over tile rectangle (center +- 8)
            float smax = A*pyc + B*pxc + C + 8.0f*(fabsf(A) + fabsf(B));
            smin = fminf(smin, smax);
        }
        // if some edge has s <= CUT_S everywhere in tile, prob <= sigmoid(CUT_S) ~ 1.1e-7
        fflag[f] = (smin > CUT_S) ? 1 : 0;
    }
    __syncthreads();

    // ---- phase 2: ordered (deterministic) compaction of surviving faces, wave 0 ----
    if (tid < 64) {
        int base = 0;
        #pragma unroll
        for (int r = 0; r < 6; ++r) {             // 6*64 = 384 >= NF
            int f = r * 64 + tid;
            bool keep = (f < NF) && (fflag[f] != 0);
            unsigned long long m = __ballot(keep);
            if (keep) {
                int pre = __popcll(m & ((1ull << tid) - 1ull));
                flist[base + pre] = (unsigned short)f;
            }
            base += __popcll(m);
        }
        if (tid == 0) fcount = base;
    }
    __syncthreads();

    // ---- phase 3: per-pixel accumulation over surviving faces ----
    const int lx = tid & 15, ly = tid >> 4;
    const float px = (float)(x0 + lx) + 0.5f;
    const float py = (float)(y0 + ly) + 0.5f;
    const int n = fcount;
    float acc = 1.0f;
    for (int i = 0; i < n; ++i) {
        const float* c = &co[(int)flist[i] * 9];
        float s0 = fmaf(c[0], py, fmaf(c[1], px, c[2]));
        float s1 = fmaf(c[3], py, fmaf(c[4], px, c[5]));
        float s2 = fmaf(c[6], py, fmaf(c[7], px, c[8]));
        float p = fast_sigmoid(s0) * fast_sigmoid(s1) * fast_sigmoid(s2);
        p = fminf(p, 0.9999f);      // clip(prob, 0, 1-1e-4); p >= 0 already
        acc *= (1.0f - p);
    }
    float sil = 1.0f - acc;
    const int gidx = b * (HH*WW) + (y0 + ly) * WW + (x0 + lx);
    float img = keep_mask[gidx] * sil;
    out_image[gidx] = img;

    // ---- masked L2 loss partial: fixed-tree deterministic reduction ----
    float d = img - image_ref[gidx];
    float sq = d * d;
    #pragma unroll
    for (int o = 32; o > 0; o >>= 1) sq += __shfl_down(sq, o);
    if ((tid & 63) == 0) wsum[tid >> 6] = sq;
    __syncthreads();
    if (tid == 0) loss_partials[blockIdx.x] = wsum[0] + wsum[1] + wsum[2] + wsum[3];
}

__global__ __launch_bounds__(512) void loss_reduce_kernel(
    const float* __restrict__ partials, float* __restrict__ out_loss)
{
    __shared__ float wsum[8];
    int tid = threadIdx.x;
    float v = partials[tid];           // exactly 512 partials
    #pragma unroll
    for (int o = 32; o > 0; o >>= 1) v += __shfl_down(v, o);
    if ((tid & 63) == 0) wsum[tid >> 6] = v;
    __syncthreads();
    if (tid == 0) {
        float sft = 0.0f;
        #pragma unroll
        for (int i = 0; i < 8; ++i) sft += wsum[i];
        out_loss[0] = sft * 0.5f;      // mean over B=2 of per-batch sums
    }
}

// edges = maxpool7x7_SAME(image) - image. Window always contains center -> no -inf.
__global__ __launch_bounds__(256) void edges_kernel(
    const float* __restrict__ image, float* __restrict__ edges)
{
    int g = blockIdx.x * 256 + threadIdx.x;   // 0 .. 2*65536-1
    int bp = g >> 16;
    int p  = g & 65535;
    int x = p & 255, y = p >> 8;
    const float* im = image + bp * 65536;
    int ylo = max(y - 3, 0), yhi = min(y + 3, HH - 1);
    int xlo = max(x - 3, 0), xhi = min(x + 3, WW - 1);
    float m = -INFINITY;
    for (int yy = ylo; yy <= yhi; ++yy) {
        const float* row = im + yy * WW;
        for (int xx = xlo; xx <= xhi; ++xx)
            m = fmaxf(m, row[xx]);
    }
    edges[g] = m - im[y * WW + x];
}

extern "C" void kernel_launch(void* const* d_in, const int* in_sizes, int n_in,
                              void* d_out, int out_size, void* d_ws, size_t ws_size,
                              hipStream_t stream) {
    const float* Rm    = (const float*)d_in[0];
    const float* obj_t = (const float*)d_in[1];
    const float* obj_s = (const float*)d_in[2];
    const float* verts = (const float*)d_in[3];
    const int*   faces = (const int*)d_in[4];
    const float* Km    = (const float*)d_in[5];
    const float* keep  = (const float*)d_in[6];
    const float* iref  = (const float*)d_in[7];
    const float* edt   = (const float*)d_in[8];

    float* out       = (float*)d_out;
    float* out_loss  = out;
    float* out_image = out + 1;
    float* out_edges = out + 1 + 131072;
    float* out_iref  = out + 1 + 262144;
    float* out_edt   = out + 1 + 393216;
    float* partials  = (float*)d_ws;      // 512 floats

    sil_tile_kernel<<<512, 256, 0, stream>>>(Rm, obj_t, obj_s, verts, faces, Km,
                                             keep, iref, out_image, partials);
    loss_reduce_kernel<<<1, 512, 0, stream>>>(partials, out_loss);
    edges_kernel<<<1024, 256, 0, stream>>>(out_image, out_edges);
    hipMemcpyAsync(out_iref, iref, 131072 * sizeof(float),
                   hipMemcpyDeviceToDevice, stream);
    hipMemcpyAsync(out_edt,  edt,  131072 * sizeof(float),
                   hipMemcpyDeviceToDevice, stream);
}

// Round 2
// 27.658 us; speedup vs baseline: 1.5117x; 1.5117x over previous
//
#include <hip/hip_runtime.h>
#include <math.h>

#define HH 256
#define WW 256
#define NF 352
#define NV 192
#define SIGMA_F 0.7f
#define CUT_S (-16.0f)

__device__ __forceinline__ float fast_sigmoid(float x) {
    // 1/(1+exp(-x)); large |x| saturates correctly (exp->inf => 0, exp->0 => 1)
    return __builtin_amdgcn_rcpf(1.0f + __expf(-x));
}

// One block = one 16x16 pixel tile of one batch image.
// Computes image = keep_mask * soft_silhouette and per-block loss partials.
__global__ __launch_bounds__(256) void sil_tile_kernel(
    const float* __restrict__ Rm, const float* __restrict__ obj_t,
    const float* __restrict__ obj_s, const float* __restrict__ verts,
    const int* __restrict__ faces, const float* __restrict__ Km,
    const float* __restrict__ keep_mask, const float* __restrict__ image_ref,
    float* __restrict__ out_image, float* __restrict__ loss_partials)
{
    __shared__ float co[NF * 9];
    __shared__ unsigned char fflag[NF];
    __shared__ unsigned short flist[NF];
    __shared__ int fcount;
    __shared__ float wsum[4];

    const int tid = threadIdx.x;
    const int b   = blockIdx.x >> 8;     // 256 tiles per batch image
    const int t   = blockIdx.x & 255;
    const int tx  = t & 15, ty = t >> 4;
    const int x0  = tx * 16, y0 = ty * 16;

    const float pxc = (float)x0 + 8.0f;  // tile center (half-extent 7.5 <= 8)
    const float pyc = (float)y0 + 8.0f;

    // ---- phase 1: per-face edge coefficients + conservative tile cull flag ----
    const float* Rb = Rm + b * 9;
    const float s  = obj_s[b];
    const float t0 = obj_t[b*3+0], t1 = obj_t[b*3+1], t2 = obj_t[b*3+2];
    const float K00 = Km[b*9+0], K02 = Km[b*9+2], K11 = Km[b*9+4], K12 = Km[b*9+5];

    for (int f = tid; f < NF; f += 256) {
        float X[3], Y[3];
        #pragma unroll
        for (int k = 0; k < 3; ++k) {
            int vi = faces[f*3 + k];
            const float* vp = verts + (b * NV + vi) * 3;
            float v0 = vp[0], v1 = vp[1], v2 = vp[2];
            float w0 = s * (v0*Rb[0] + v1*Rb[3] + v2*Rb[6] + t0);
            float w1 = s * (v0*Rb[1] + v1*Rb[4] + v2*Rb[7] + t1);
            float w2 = s * (v0*Rb[2] + v1*Rb[5] + v2*Rb[8] + t2);
            X[k] = (K00 * w0 / w2 + K02) * (float)WW;
            Y[k] = (K11 * w1 / w2 + K12) * (float)HH;
        }
        float e01x = X[1]-X[0], e01y = Y[1]-Y[0];
        float e02x = X[2]-X[0], e02y = Y[2]-Y[0];
        float area2 = e01x*e02y - e01y*e02x;
        float orient = (area2 >= 0.0f) ? 1.0f : -1.0f;
        float smin = 1e30f;
        #pragma unroll
        for (int k = 0; k < 3; ++k) {
            int k1 = (k == 2) ? 0 : k + 1;
            float ax = X[k], ay = Y[k];
            float ex = X[k1]-ax, ey = Y[k1]-ay;
            float inv = orient / (sqrtf(ex*ex + ey*ey) + 1e-8f) / SIGMA_F;
            float A = ex * inv;
            float B = -ey * inv;
            float C = inv * (ey*ax - ex*ay);
            co[f*9 + k*3 + 0] = A;
            co[f*9 + k*3 + 1] = B;
            co[f*9 + k*3 + 2] = C;
            // exact max of affine s over tile rectangle (center +- 8)
            float smax = A*pyc + B*pxc + C + 8.0f*(fabsf(A) + fabsf(B));
            smin = fminf(smin, smax);
        }
        // if some edge has s <= CUT_S everywhere in tile, prob <= sigmoid(CUT_S) ~ 1.1e-7
        fflag[f] = (smin > CUT_S) ? 1 : 0;
    }
    __syncthreads();

    // ---- phase 2: ordered (deterministic) compaction of surviving faces, wave 0 ----
    if (tid < 64) {
        int base = 0;
        #pragma unroll
        for (int r = 0; r < 6; ++r) {             // 6*64 = 384 >= NF
            int f = r * 64 + tid;
            bool keep = (f < NF) && (fflag[f] != 0);
            unsigned long long m = __ballot(keep);
            if (keep) {
                int pre = __popcll(m & ((1ull << tid) - 1ull));
                flist[base + pre] = (unsigned short)f;
            }
            base += __popcll(m);
        }
        if (tid == 0) fcount = base;
    }
    __syncthreads();

    // ---- phase 3: per-pixel accumulation over surviving faces ----
    const int lx = tid & 15, ly = tid >> 4;
    const float px = (float)(x0 + lx) + 0.5f;
    const float py = (float)(y0 + ly) + 0.5f;
    const int n = fcount;
    float acc = 1.0f;
    for (int i = 0; i < n; ++i) {
        const float* c = &co[(int)flist[i] * 9];
        float s0 = fmaf(c[0], py, fmaf(c[1], px, c[2]));
        float s1 = fmaf(c[3], py, fmaf(c[4], px, c[5]));
        float s2 = fmaf(c[6], py, fmaf(c[7], px, c[8]));
        float p = fast_sigmoid(s0) * fast_sigmoid(s1) * fast_sigmoid(s2);
        p = fminf(p, 0.9999f);      // clip(prob, 0, 1-1e-4); p >= 0 already
        acc *= (1.0f - p);
    }
    float sil = 1.0f - acc;
    const int gidx = b * (HH*WW) + (y0 + ly) * WW + (x0 + lx);
    float img = keep_mask[gidx] * sil;
    out_image[gidx] = img;

    // ---- masked L2 loss partial: fixed-tree deterministic reduction ----
    float d = img - image_ref[gidx];
    float sq = d * d;
    #pragma unroll
    for (int o = 32; o > 0; o >>= 1) sq += __shfl_down(sq, o);
    if ((tid & 63) == 0) wsum[tid >> 6] = sq;
    __syncthreads();
    if (tid == 0) loss_partials[blockIdx.x] = wsum[0] + wsum[1] + wsum[2] + wsum[3];
}

// Fused: edges (separable 7x7 maxpool - image), passthrough copies, final loss.
// One block = one 16x16 tile (512 blocks); block 0 additionally reduces the loss.
__global__ __launch_bounds__(256) void post_kernel(
    const float* __restrict__ image, const float* __restrict__ partials,
    const float* __restrict__ iref, const float* __restrict__ edt,
    float* __restrict__ out_loss, float* __restrict__ out_edges,
    float* __restrict__ out_iref, float* __restrict__ out_edt)
{
    __shared__ float tile[22][23];     // 16+2*3 halo, +1 col pad
    __shared__ float rmax[22][16];     // row-max over 7-wide window
    __shared__ float lsum[4];

    const int tid = threadIdx.x;
    const int b   = blockIdx.x >> 8;
    const int t   = blockIdx.x & 255;
    const int x0  = (t & 15) * 16, y0 = (t >> 4) * 16;
    const float* im = image + b * (HH*WW);

    // load 22x22 halo tile (OOB -> -inf; window always contains center pixel)
    for (int i = tid; i < 22*22; i += 256) {
        int r = i / 22, cidx = i % 22;
        int yy = y0 + r - 3, xx = x0 + cidx - 3;
        float v = -INFINITY;
        if (yy >= 0 && yy < HH && xx >= 0 && xx < WW) v = im[yy * WW + xx];
        tile[r][cidx] = v;
    }
    __syncthreads();

    // row pass: rmax[r][c] = max(tile[r][c .. c+6]), 22*16 = 352 entries
    for (int i = tid; i < 22*16; i += 256) {
        int r = i >> 4, c = i & 15;
        float m = tile[r][c];
        #pragma unroll
        for (int d = 1; d < 7; ++d) m = fmaxf(m, tile[r][c + d]);
        rmax[r][c] = m;
    }
    __syncthreads();

    // col pass + write edges
    const int lx = tid & 15, ly = tid >> 4;
    float m = rmax[ly][lx];
    #pragma unroll
    for (int d = 1; d < 7; ++d) m = fmaxf(m, rmax[ly + d][lx]);
    const int gidx = b * (HH*WW) + (y0 + ly) * WW + (x0 + lx);
    out_edges[gidx] = m - tile[ly + 3][lx + 3];

    // passthrough copies (coalesced, one element per thread per array)
    const int g = blockIdx.x * 256 + tid;     // 0 .. 131071
    out_iref[g] = iref[g];
    out_edt[g]  = edt[g];

    // final loss reduction (block 0 only; partials were written by sil_tile_kernel)
    if (blockIdx.x == 0) {
        float v = partials[tid] + partials[tid + 256];
        #pragma unroll
        for (int o = 32; o > 0; o >>= 1) v += __shfl_down(v, o);
        if ((tid & 63) == 0) lsum[tid >> 6] = v;
        __syncthreads();
        if (tid == 0)
            out_loss[0] = (lsum[0] + lsum[1] + lsum[2] + lsum[3]) * 0.5f; // mean over B=2
    }
}

extern "C" void kernel_launch(void* const* d_in, const int* in_sizes, int n_in,
                              void* d_out, int out_size, void* d_ws, size_t ws_size,
                              hipStream_t stream) {
    const float* Rm    = (const float*)d_in[0];
    const float* obj_t = (const float*)d_in[1];
    const float* obj_s = (const float*)d_in[2];
    const float* verts = (const float*)d_in[3];
    const int*   faces = (const int*)d_in[4];
    const float* Km    = (const float*)d_in[5];
    const float* keep  = (const float*)d_in[6];
    const float* iref  = (const float*)d_in[7];
    const float* edt   = (const float*)d_in[8];

    float* out       = (float*)d_out;
    float* out_loss  = out;
    float* out_image = out + 1;
    float* out_edges = out + 1 + 131072;
    float* out_iref  = out + 1 + 262144;
    float* out_edt   = out + 1 + 393216;
    float* partials  = (float*)d_ws;      // 512 floats

    sil_tile_kernel<<<512, 256, 0, stream>>>(Rm, obj_t, obj_s, verts, faces, Km,
                                             keep, iref, out_image, partials);
    post_kernel<<<512, 256, 0, stream>>>(out_image, partials, iref, edt,
                                         out_loss, out_edges, out_iref, out_edt);
}

// Round 3
// 21.570 us; speedup vs baseline: 1.9383x; 1.2822x over previous
//
#include <hip/hip_runtime.h>
#include <math.h>

#define HH 256
#define WW 256
#define NF 352
#define NV 192
#define L2E 1.44269504f
// cull threshold: natural -16 => log2 domain -16*log2(e)
#define CUT_T (-23.0831f)

// One block = one 16x16 pixel tile; each of the 4 waves owns an 8x8 subtile.
__global__ __launch_bounds__(256) void sil_tile_kernel(
    const float* __restrict__ Rm, const float* __restrict__ obj_t,
    const float* __restrict__ obj_s, const float* __restrict__ verts,
    const int* __restrict__ faces, const float* __restrict__ Km,
    const float* __restrict__ keep_mask, const float* __restrict__ image_ref,
    const float* __restrict__ iref_src, const float* __restrict__ edt_src,
    float* __restrict__ out_image, float* __restrict__ loss_partials,
    float* __restrict__ out_iref, float* __restrict__ out_edt)
{
    __shared__ float co[NF * 9];              // log2e-scaled edge coefficients
    __shared__ unsigned short flist[4][NF];   // per-subtile surviving faces
    __shared__ int fcount[4];
    __shared__ float wsum[4];

    const int tid  = threadIdx.x;
    const int lane = tid & 63;
    const int wv   = tid >> 6;
    const int b    = blockIdx.x >> 8;     // 256 tiles per batch image
    const int t    = blockIdx.x & 255;
    const int x0   = (t & 15) * 16, y0 = (t >> 4) * 16;

    // ---- phase 1: per-face edge coefficients (block-shared) ----
    const float* Rb = Rm + b * 9;
    const float s  = obj_s[b];
    const float t0 = obj_t[b*3+0], t1 = obj_t[b*3+1], t2 = obj_t[b*3+2];
    const float K00 = Km[b*9+0], K02 = Km[b*9+2], K11 = Km[b*9+4], K12 = Km[b*9+5];

    for (int f = tid; f < NF; f += 256) {
        float X[3], Y[3];
        #pragma unroll
        for (int k = 0; k < 3; ++k) {
            int vi = faces[f*3 + k];
            const float* vp = verts + (b * NV + vi) * 3;
            float v0 = vp[0], v1 = vp[1], v2 = vp[2];
            float w0 = s * (v0*Rb[0] + v1*Rb[3] + v2*Rb[6] + t0);
            float w1 = s * (v0*Rb[1] + v1*Rb[4] + v2*Rb[7] + t1);
            float w2 = s * (v0*Rb[2] + v1*Rb[5] + v2*Rb[8] + t2);
            float rz = __builtin_amdgcn_rcpf(w2);
            X[k] = (K00 * w0 * rz + K02) * (float)WW;
            Y[k] = (K11 * w1 * rz + K12) * (float)HH;
        }
        float e01x = X[1]-X[0], e01y = Y[1]-Y[0];
        float e02x = X[2]-X[0], e02y = Y[2]-Y[0];
        float area2 = e01x*e02y - e01y*e02x;
        float orient = (area2 >= 0.0f) ? L2E : -L2E;   // fold log2(e) here
        #pragma unroll
        for (int k = 0; k < 3; ++k) {
            int k1 = (k == 2) ? 0 : k + 1;
            float ax = X[k], ay = Y[k];
            float ex = X[k1]-ax, ey = Y[k1]-ay;
            float inv = orient / ((sqrtf(ex*ex + ey*ey) + 1e-8f) * 0.7f);
            co[f*9 + k*3 + 0] = ex * inv;               // A (coeff of py)
            co[f*9 + k*3 + 1] = -ey * inv;              // B (coeff of px)
            co[f*9 + k*3 + 2] = inv * (ey*ax - ex*ay);  // C
        }
    }
    __syncthreads();

    // ---- phase 2: per-wave subtile cull + ordered compaction ----
    const int sx = (wv & 1) * 8, sy = (wv >> 1) * 8;
    const float pxc = (float)(x0 + sx) + 4.0f;   // subtile center (half-ext 3.5<=4)
    const float pyc = (float)(y0 + sy) + 4.0f;
    {
        int base = 0;
        #pragma unroll
        for (int r = 0; r < 6; ++r) {            // 6*64 = 384 >= NF
            int f = r * 64 + lane;
            bool keep = false;
            if (f < NF) {
                float smin = 1e30f;
                #pragma unroll
                for (int k = 0; k < 3; ++k) {
                    float A = co[f*9 + k*3 + 0];
                    float B = co[f*9 + k*3 + 1];
                    float C = co[f*9 + k*3 + 2];
                    float smax = fmaf(A, pyc, fmaf(B, pxc, C)) + 4.0f*(fabsf(A) + fabsf(B));
                    smin = fminf(smin, smax);
                }
                keep = (smin > CUT_T);
            }
            unsigned long long m = __ballot(keep);
            if (keep) {
                int pre = __popcll(m & ((1ull << lane) - 1ull));
                flist[wv][base + pre] = (unsigned short)f;
            }
            base += __popcll(m);
        }
        if (lane == 0) fcount[wv] = base;
    }
    // no barrier needed: each wave reads only its own flist/fcount
    const int n = fcount[wv];

    // ---- phase 3: per-lane pixel, loop surviving faces ----
    const int lx = lane & 7, ly = lane >> 3;
    const float px = (float)(x0 + sx + lx) + 0.5f;
    const float py = (float)(y0 + sy + ly) + 0.5f;
    float acc = 1.0f;
    for (int i = 0; i < n; ++i) {
        const float* c = &co[(int)flist[wv][i] * 9];
        float u0 = fmaf(c[0], py, fmaf(c[1], px, c[2]));
        float u1 = fmaf(c[3], py, fmaf(c[4], px, c[5]));
        float u2 = fmaf(c[6], py, fmaf(c[7], px, c[8]));
        // prob = sig(u0)sig(u1)sig(u2) = 1 / ((1+2^-u0)(1+2^-u1)(1+2^-u2))
        float e0 = __builtin_amdgcn_exp2f(-u0);
        float e1 = __builtin_amdgcn_exp2f(-u1);
        float e2 = __builtin_amdgcn_exp2f(-u2);
        float den = (1.0f + e0) * (1.0f + e1) * (1.0f + e2);
        float p = __builtin_amdgcn_rcpf(den);   // inf -> 0: far-outside ok
        p = fminf(p, 0.9999f);                  // clip(prob, 0, 1-1e-4)
        acc *= (1.0f - p);
    }
    float sil = 1.0f - acc;
    const int gidx = b * (HH*WW) + (y0 + sy + ly) * WW + (x0 + sx + lx);
    float img = keep_mask[gidx] * sil;
    out_image[gidx] = img;

    // ---- passthrough copies (coalesced) ----
    const int g = blockIdx.x * 256 + tid;
    out_iref[g] = iref_src[g];
    out_edt[g]  = edt_src[g];

    // ---- masked L2 loss partial: fixed-tree deterministic reduction ----
    float d = img - image_ref[gidx];
    float sq = d * d;
    #pragma unroll
    for (int o = 32; o > 0; o >>= 1) sq += __shfl_down(sq, o);
    if (lane == 0) wsum[wv] = sq;
    __syncthreads();
    if (tid == 0) loss_partials[blockIdx.x] = wsum[0] + wsum[1] + wsum[2] + wsum[3];
}

// edges (separable 7x7 maxpool - image) + final loss reduce in block 0.
__global__ __launch_bounds__(256) void post_kernel(
    const float* __restrict__ image, const float* __restrict__ partials,
    float* __restrict__ out_loss, float* __restrict__ out_edges)
{
    __shared__ float tile[22][23];     // 16+2*3 halo, +1 col pad
    __shared__ float rmax[22][16];     // row-max over 7-wide window
    __shared__ float lsum[4];

    const int tid = threadIdx.x;
    const int b   = blockIdx.x >> 8;
    const int t   = blockIdx.x & 255;
    const int x0  = (t & 15) * 16, y0 = (t >> 4) * 16;
    const float* im = image + b * (HH*WW);

    // load 22x22 halo tile (OOB -> -inf; window always contains center pixel)
    for (int i = tid; i < 22*22; i += 256) {
        int r = i / 22, cidx = i % 22;
        int yy = y0 + r - 3, xx = x0 + cidx - 3;
        float v = -INFINITY;
        if (yy >= 0 && yy < HH && xx >= 0 && xx < WW) v = im[yy * WW + xx];
        tile[r][cidx] = v;
    }
    __syncthreads();

    // row pass
    for (int i = tid; i < 22*16; i += 256) {
        int r = i >> 4, c = i & 15;
        float m = tile[r][c];
        #pragma unroll
        for (int d = 1; d < 7; ++d) m = fmaxf(m, tile[r][c + d]);
        rmax[r][c] = m;
    }
    __syncthreads();

    // col pass + write edges
    const int lx = tid & 15, ly = tid >> 4;
    float m = rmax[ly][lx];
    #pragma unroll
    for (int d = 1; d < 7; ++d) m = fmaxf(m, rmax[ly + d][lx]);
    const int gidx = b * (HH*WW) + (y0 + ly) * WW + (x0 + lx);
    out_edges[gidx] = m - tile[ly + 3][lx + 3];

    // final loss reduction (block 0 only)
    if (blockIdx.x == 0) {
        float v = partials[tid] + partials[tid + 256];
        #pragma unroll
        for (int o = 32; o > 0; o >>= 1) v += __shfl_down(v, o);
        if ((tid & 63) == 0) lsum[tid >> 6] = v;
        __syncthreads();
        if (tid == 0)
            out_loss[0] = (lsum[0] + lsum[1] + lsum[2] + lsum[3]) * 0.5f; // mean over B=2
    }
}

extern "C" void kernel_launch(void* const* d_in, const int* in_sizes, int n_in,
                              void* d_out, int out_size, void* d_ws, size_t ws_size,
                              hipStream_t stream) {
    const float* Rm    = (const float*)d_in[0];
    const float* obj_t = (const float*)d_in[1];
    const float* obj_s = (const float*)d_in[2];
    const float* verts = (const float*)d_in[3];
    const int*   faces = (const int*)d_in[4];
    const float* Km    = (const float*)d_in[5];
    const float* keep  = (const float*)d_in[6];
    const float* iref  = (const float*)d_in[7];
    const float* edt   = (const float*)d_in[8];

    float* out       = (float*)d_out;
    float* out_loss  = out;
    float* out_image = out + 1;
    float* out_edges = out + 1 + 131072;
    float* out_iref  = out + 1 + 262144;
    float* out_edt   = out + 1 + 393216;
    float* partials  = (float*)d_ws;      // 512 floats

    sil_tile_kernel<<<512, 256, 0, stream>>>(Rm, obj_t, obj_s, verts, faces, Km,
                                             keep, iref, iref, edt,
                                             out_image, partials, out_iref, out_edt);
    post_kernel<<<512, 256, 0, stream>>>(out_image, partials, out_loss, out_edges);
}